// Round 18
// baseline (138.312 us; speedup 1.0000x reference)
//
#include <hip/hip_runtime.h>
#include <math.h>

#define N_SP 2304   // 48*48 spatial
#define HW 48

typedef unsigned short u16;
typedef short s8v  __attribute__((ext_vector_type(8)));   // bf16x8 (MFMA operand)
typedef short s4v  __attribute__((ext_vector_type(4)));   // bf16x4
typedef u16   u16x8 __attribute__((ext_vector_type(8)));
typedef float f32x4 __attribute__((ext_vector_type(4)));
typedef unsigned u32x4 __attribute__((ext_vector_type(4)));

__device__ __forceinline__ short f2bf(float x) {
    unsigned u = __float_as_uint(x);
    u += 0x7FFFu + ((u >> 16) & 1u);
    return (short)(u >> 16);
}
__device__ __forceinline__ float bf2f(u16 u) {
    return __uint_as_float((unsigned)u << 16);
}
__device__ __forceinline__ float fexp2(float x) { return __builtin_amdgcn_exp2f(x); }
__device__ __forceinline__ float frcp(float x)  { return __builtin_amdgcn_rcpf(x); }
__device__ __forceinline__ float fsilu(float v) {
    return v * frcp(1.f + fexp2(-1.4426950408889634f * v));
}
__device__ __forceinline__ unsigned cvtpk(float lo, float hi) {  // 2xf32 -> packed bf16
    unsigned r;
    asm("v_cvt_pk_bf16_f32 %0, %1, %2" : "=v"(r) : "v"(lo), "v"(hi));
    return r;
}
__device__ __forceinline__ void gload16(const void* g, void* l) {
    __builtin_amdgcn_global_load_lds(
        (const __attribute__((address_space(1))) void*)g,
        (__attribute__((address_space(3))) void*)l, 16, 0, 0);
}
// raw barrier WITHOUT vmcnt drain (keeps prefetch loads in flight)
__device__ __forceinline__ void bar_lgkm() {
    asm volatile("s_waitcnt lgkmcnt(0)" ::: "memory");
    __builtin_amdgcn_s_barrier();
}

// ---------------------------------------------------------------------------
// prep: merged weight fp32->bf16 convert (blocks 0..959) and x transpose
// (blocks 960..2111): x [b][512][2304] fp32 -> xT [b][2304][512] bf16.
// ---------------------------------------------------------------------------
__global__ __launch_bounds__(256) void prep(
    const float* __restrict__ X, u16* __restrict__ XT,
    const float* __restrict__ s0, const float* __restrict__ s1,
    const float* __restrict__ s2, const float* __restrict__ s3,
    const float* __restrict__ s4, const float* __restrict__ s5,
    u16* __restrict__ d0, u16* __restrict__ d1, u16* __restrict__ d2,
    u16* __restrict__ d3, u16* __restrict__ d4, u16* __restrict__ d5)
{
    __shared__ float tile[64][65];
    const int t = threadIdx.x;
    if (blockIdx.x < 960) {
        int id = blockIdx.x * 256 + t;   // float4 index
        const int c0 = 65536, c1 = c0 + 32768, c2 = c1 + 16384,
                  c3 = c2 + 32768, c4 = c3 + 32768, c5 = c4 + 65536;
        if (id >= c5) return;
        const float* s; u16* d; int off;
        if      (id < c0) { s = s0; d = d0; off = id; }
        else if (id < c1) { s = s1; d = d1; off = id - c0; }
        else if (id < c2) { s = s2; d = d2; off = id - c1; }
        else if (id < c3) { s = s3; d = d3; off = id - c2; }
        else if (id < c4) { s = s4; d = d4; off = id - c3; }
        else              { s = s5; d = d5; off = id - c4; }
        float4 v = ((const float4*)s)[off];
        s4v p; p[0] = f2bf(v.x); p[1] = f2bf(v.y); p[2] = f2bf(v.z); p[3] = f2bf(v.w);
        ((s4v*)d)[off] = p;
        return;
    }
    // transpose part: 1152 blocks = 36 x 8 x 4
    const int bid = blockIdx.x - 960;
    const int n0 = (bid % 36) * 64, c0 = ((bid / 36) & 7) * 64, b = bid / 288;
    const float* src = X + (long)b * 512 * N_SP;
    u16* dst = XT + (long)b * N_SP * 512;
    #pragma unroll
    for (int it = 0; it < 16; ++it) {
        int id = t + 256 * it;
        int cl = id >> 6, nl = id & 63;
        tile[cl][nl] = src[(long)(c0 + cl) * N_SP + n0 + nl];
    }
    __syncthreads();
    #pragma unroll
    for (int it = 0; it < 16; ++it) {
        int id = t + 256 * it;
        int nl = id >> 6, cl = id & 63;
        dst[(long)(n0 + nl) * 512 + c0 + cl] = f2bf(tile[cl][nl]);
    }
}

// ---------------------------------------------------------------------------
// Shared GEMM epilogue (scale/bias/silu/residual + output modes).
// ---------------------------------------------------------------------------
template <int OMODE>
__device__ __forceinline__ void gemm_epilogue(
    float y[4], int nb, int nib, int o, int b_blk, int Mtot,
    const u16* Res, int sR, void* OutP, u16* OutT, int sO)
{
    if (Res) {
        #pragma unroll
        for (int r = 0; r < 4; ++r)
            y[r] += bf2f(Res[(long)(nb + r) * sR + o]);
    }
    if (OMODE == 0) {
        u16* O = (u16*)OutP;
        #pragma unroll
        for (int r = 0; r < 4; ++r)
            O[(long)(nb + r) * sO + o] = (u16)f2bf(y[r]);
    } else if (OMODE == 1 || OMODE == 3) {
        u16* O = (u16*)OutP + (long)b_blk * Mtot * N_SP + (long)o * N_SP + nib;
        s4v pk;
        #pragma unroll
        for (int r = 0; r < 4; ++r) pk[r] = f2bf(y[r]);
        *(s4v*)O = pk;
        if (OMODE == 3) {
            #pragma unroll
            for (int r = 0; r < 4; ++r)
                OutT[(long)(nb + r) * 512 + o] = (u16)f2bf(y[r]);
        }
    } else {
        float* O = (float*)OutP + (long)b_blk * Mtot * N_SP + (long)o * N_SP + nib;
        *(float4*)O = make_float4(y[0], y[1], y[2], y[3]);
    }
}

// ---------------------------------------------------------------------------
// MFMA GEMM (64x64 tile, BK=64, 3-buffer counted vmcnt(4)) — used for the
// M=256 GEMMs (proj, ffn2; grid 576 = 2.25/CU, single-round).
// XCD-clustered 1D grid.
// ---------------------------------------------------------------------------
template <int NO, int OMODE>
__global__ __launch_bounds__(256) void mfma_gemm(
    const u16* __restrict__ A1, const u16* __restrict__ A2, int K1,
    int sA1, int sA2, int K,
    const u16* __restrict__ W,
    const float* __restrict__ S, const float* __restrict__ Bi,
    const u16* __restrict__ Res, int sR,
    void* __restrict__ OutP, u16* __restrict__ OutT, int sO, int Mtot,
    int act)
{
    __shared__ u16 Al[3][64][64];
    __shared__ u16 Bl[3][64][64];
    const int t  = threadIdx.x;
    const int p = blockIdx.x;
    const int cx = p & 7, q = p >> 3;
    const int n0 = (cx * 18 + q / NO) * 64;
    const int o0 = (q % NO) * 64;
    const int lane = t & 63, w = t >> 6;
    const int wn = (w & 1) * 32, wo = (w >> 1) * 32;
    const int li = lane & 15, g = lane >> 4;

    const int b_blk = n0 / N_SP;
    const int n_in0 = n0 - b_blk * N_SP;

    f32x4 acc[2][2];
    #pragma unroll
    for (int fm = 0; fm < 2; ++fm)
        #pragma unroll
        for (int fn = 0; fn < 2; ++fn) acc[fm][fn] = f32x4{0.f, 0.f, 0.f, 0.f};

    auto issue = [&](int buf, int k0) {
        #pragma unroll
        for (int qq = 0; qq < 2; ++qq) {
            int c = t + qq * 256;
            int row = c >> 3;
            int col = ((c & 7) ^ (row & 7)) * 8;   // inverse-swizzled source
            int kk = k0 + col;
            const u16* ga = (kk < K1) ? (A1 + (long)(n0 + row) * sA1 + kk)
                                      : (A2 + (long)(n0 + row) * sA2 + (kk - K1));
            gload16(ga, (u16*)Al[buf] + (qq * 256 + w * 64) * 8);
            gload16(W + (long)(o0 + row) * K + k0 + col,
                    (u16*)Bl[buf] + (qq * 256 + w * 64) * 8);
        }
    };

    const int NK = K >> 6;
    issue(0, 0);
    if (NK > 1) issue(1, 64);

    for (int ks = 0; ks < NK; ++ks) {
        if (ks + 1 < NK) asm volatile("s_waitcnt vmcnt(4)" ::: "memory");
        else             asm volatile("s_waitcnt vmcnt(0)" ::: "memory");
        __builtin_amdgcn_s_barrier();
        if (ks + 2 < NK) issue((ks + 2) % 3, (ks + 2) << 6);
        const int cur = ks % 3;
        #pragma unroll
        for (int k2 = 0; k2 < 2; ++k2) {
            s8v af[2], bfv[2];
            #pragma unroll
            for (int fm = 0; fm < 2; ++fm) {
                int row = wn + fm * 16 + li;
                af[fm] = *(const s8v*)&Al[cur][row][((g + 4 * k2) ^ (li & 7)) * 8];
            }
            #pragma unroll
            for (int fn = 0; fn < 2; ++fn) {
                int row = wo + fn * 16 + li;
                bfv[fn] = *(const s8v*)&Bl[cur][row][((g + 4 * k2) ^ (li & 7)) * 8];
            }
            #pragma unroll
            for (int fm = 0; fm < 2; ++fm)
                #pragma unroll
                for (int fn = 0; fn < 2; ++fn)
                    acc[fm][fn] = __builtin_amdgcn_mfma_f32_16x16x32_bf16(
                        af[fm], bfv[fn], acc[fm][fn], 0, 0, 0);
        }
    }

    #pragma unroll
    for (int fn = 0; fn < 2; ++fn) {
        const int o = o0 + wo + fn * 16 + li;
        const float sc2 = S[o], bi = Bi[o];
        #pragma unroll
        for (int fm = 0; fm < 2; ++fm) {
            const int nb  = n0 + wn + fm * 16 + 4 * g;
            const int nib = n_in0 + wn + fm * 16 + 4 * g;
            float y[4];
            #pragma unroll
            for (int r = 0; r < 4; ++r) {
                float v = acc[fm][fn][r] * sc2 + bi;
                if (act) v = fsilu(v);
                y[r] = v;
            }
            gemm_epilogue<OMODE>(y, nb, nib, o, b_blk, Mtot, Res, sR, OutP, OutT, sO);
        }
    }
}

// ---------------------------------------------------------------------------
// BIG MFMA GEMM (128n x 64o tile, BK=64) — M=512 GEMMs. R17: 3-buffer
// pipeline with COUNTED vmcnt(6) (T4): issue 2 K-steps ahead; per step
// {vmcnt(6) -> s_barrier -> issue(ks+2) -> 32 MFMA}. vmcnt never drains to
// 0 in steady state (R16's 2-phase drained 6 loads with only ~200cyc cover
// -> ~300-700cyc naked drain/step). 72 KB LDS -> 2 blocks/CU.
// ---------------------------------------------------------------------------
template <int NO, int OMODE>
__global__ __launch_bounds__(256) void mfma_gemm_big(
    const u16* __restrict__ A1, const u16* __restrict__ A2, int K1,
    int sA1, int sA2, int K,
    const u16* __restrict__ W,
    const float* __restrict__ S, const float* __restrict__ Bi,
    const u16* __restrict__ Res, int sR,
    void* __restrict__ OutP, u16* __restrict__ OutT, int sO, int Mtot,
    int act)
{
    __shared__ u16 Al[3][128][64];
    __shared__ u16 Bl[3][64][64];
    const int t  = threadIdx.x;
    const int p = blockIdx.x;
    const int cx = p & 7, q = p >> 3;
    const int n0 = (cx * 9 + q / NO) * 128;   // 72 n-tiles = 8 XCD cls x 9
    const int o0 = (q % NO) * 64;
    const int lane = t & 63, w = t >> 6;
    const int wn = (w & 1) * 64, wo = (w >> 1) * 32;
    const int li = lane & 15, g = lane >> 4;

    const int b_blk = n0 / N_SP;              // 2304 % 128 == 0
    const int n_in0 = n0 - b_blk * N_SP;

    f32x4 acc[4][2];
    #pragma unroll
    for (int fm = 0; fm < 4; ++fm)
        #pragma unroll
        for (int fn = 0; fn < 2; ++fn) acc[fm][fn] = f32x4{0.f, 0.f, 0.f, 0.f};

    auto issue = [&](int buf, int k0) {
        #pragma unroll
        for (int qq = 0; qq < 4; ++qq) {
            int c = t + qq * 256;
            int row = c >> 3;
            int col = ((c & 7) ^ (row & 7)) * 8;   // inverse-swizzled source
            int kk = k0 + col;
            const u16* ga = (kk < K1) ? (A1 + (long)(n0 + row) * sA1 + kk)
                                      : (A2 + (long)(n0 + row) * sA2 + (kk - K1));
            gload16(ga, (u16*)Al[buf] + (qq * 256 + w * 64) * 8);
        }
        #pragma unroll
        for (int qq = 0; qq < 2; ++qq) {
            int c = t + qq * 256;
            int row = c >> 3;
            int col = ((c & 7) ^ (row & 7)) * 8;
            gload16(W + (long)(o0 + row) * K + k0 + col,
                    (u16*)Bl[buf] + (qq * 256 + w * 64) * 8);
        }
    };

    const int NK = K >> 6;
    issue(0, 0);
    if (NK > 1) issue(1, 64);

    for (int ks = 0; ks < NK; ++ks) {
        if (ks + 1 < NK) asm volatile("s_waitcnt vmcnt(6)" ::: "memory");
        else             asm volatile("s_waitcnt vmcnt(0)" ::: "memory");
        __builtin_amdgcn_s_barrier();             // buf[ks%3] ready block-wide
        if (ks + 2 < NK) issue((ks + 2) % 3, (ks + 2) << 6);
        const int cur = ks % 3;
        #pragma unroll
        for (int k2 = 0; k2 < 2; ++k2) {
            s8v af[4], bfv[2];
            #pragma unroll
            for (int fm = 0; fm < 4; ++fm) {
                int row = wn + fm * 16 + li;               // row&7 == li&7
                af[fm] = *(const s8v*)&Al[cur][row][((g + 4 * k2) ^ (li & 7)) * 8];
            }
            #pragma unroll
            for (int fn = 0; fn < 2; ++fn) {
                int row = wo + fn * 16 + li;
                bfv[fn] = *(const s8v*)&Bl[cur][row][((g + 4 * k2) ^ (li & 7)) * 8];
            }
            #pragma unroll
            for (int fm = 0; fm < 4; ++fm)
                #pragma unroll
                for (int fn = 0; fn < 2; ++fn)
                    acc[fm][fn] = __builtin_amdgcn_mfma_f32_16x16x32_bf16(
                        af[fm], bfv[fn], acc[fm][fn], 0, 0, 0);
        }
    }

    #pragma unroll
    for (int fn = 0; fn < 2; ++fn) {
        const int o = o0 + wo + fn * 16 + li;
        const float sc2 = S[o], bi = Bi[o];
        #pragma unroll
        for (int fm = 0; fm < 4; ++fm) {
            const int nb  = n0 + wn + fm * 16 + 4 * g;
            const int nib = n_in0 + wn + fm * 16 + 4 * g;
            float y[4];
            #pragma unroll
            for (int r = 0; r < 4; ++r) {
                float v = acc[fm][fn][r] * sc2 + bi;
                if (act) v = fsilu(v);
                y[r] = v;
            }
            gemm_epilogue<OMODE>(y, nb, nib, o, b_blk, Mtot, Res, sR, OutP, OutT, sO);
        }
    }
}

// ---------------------------------------------------------------------------
// MFMA flash attention, split-j x4, 2 q-frags/wave (128 queries/block).
// Q/K from qkvT (b128 loads), V from qkvb. Double-buffered LDS, one raw
// barrier per tile, XCD-clustered grid, setprio around MFMA clusters.
// R16 shuffle-free softmax: local-max + __any ballot defer check; l kept as
// per-lane partial, reduced once in the epilogue.
// ---------------------------------------------------------------------------
__global__ __launch_bounds__(256) void attn_mfma(const u16* __restrict__ qkv,
    const u16* __restrict__ qkvT,
    u16* __restrict__ Opart, float* __restrict__ mpart, float* __restrict__ lpart)
{
    const int N = N_SP;
    __shared__ u16 Klds[2][64][40];   // [j][d]
    __shared__ u16 Vlds[2][64][72];   // [d][j]

    const int p = blockIdx.x;
    const int cx = p & 7, q = p >> 3;
    const int i0 = (q % 18) * 128;
    const int bhz = cx + 8 * (q / 18);     // 0..63
    const int bh = bhz & 15, z = bhz >> 4; // z = j-chunk 0..3
    const int b = bh >> 2, h = bh & 3;
    const int t = threadIdx.x;
    const int w = t >> 6;
    const int lane = t & 63;
    const int li = lane & 15;
    const int g  = lane >> 4;
    const float qscale = 0.17677669529663687f * 1.4426950408889634f;

    const u16* qp  = qkv  + ((long)b * 512 + (long)h * 128) * N;
    const u16* vp  = qp + 64L * N;
    const u16* qTp = qkvT + (long)b * N * 512 + h * 128;

    const int ia = i0 + w * 16 + li;     // q-frag 0
    const int ib = ia + 64;              // q-frag 1

    s8v qf[2];
    {
        s8v qa = *(const s8v*)(qTp + (long)ia * 512 + 8 * g);
        s8v qb = *(const s8v*)(qTp + (long)ib * 512 + 8 * g);
        #pragma unroll
        for (int r = 0; r < 8; ++r) {
            qf[0][r] = f2bf(bf2f((u16)qa[r]) * qscale);
            qf[1][r] = f2bf(bf2f((u16)qb[r]) * qscale);
        }
    }

    f32x4 oacc[2][4];
    #pragma unroll
    for (int q2 = 0; q2 < 2; ++q2)
        #pragma unroll
        for (int dt = 0; dt < 4; ++dt) oacc[q2][dt] = f32x4{0.f, 0.f, 0.f, 0.f};
    float m_run[2] = {-1e30f, -1e30f}, l_run[2] = {0.f, 0.f};  // l: per-lane partial

    const int kj2 = t & 63;            // j within tile (K staging)
    const int kd  = (t >> 6) * 8;      // 8-d chunk
    const int vd  = t >> 2;            // 0..63
    const int vjb = (t & 3) * 16;      // 0..48

    const int jbase = z * 576;
    u16x8 kr, vr0, vr1;
    auto ldregs = [&](int j0) {
        kr  = *(const u16x8*)(qTp + (long)(j0 + kj2) * 512 + 32 + kd);
        vr0 = *(const u16x8*)(vp + (long)vd * N + j0 + vjb);
        vr1 = *(const u16x8*)(vp + (long)vd * N + j0 + vjb + 8);
    };

    ldregs(jbase);
    *(u16x8*)&Klds[0][kj2][kd]     = kr;
    *(u16x8*)&Vlds[0][vd][vjb]     = vr0;
    *(u16x8*)&Vlds[0][vd][vjb + 8] = vr1;
    ldregs(jbase + 64);
    bar_lgkm();

    int cur = 0;
    for (int it = 0; it < 9; ++it) {
        if (it + 1 < 9) {
            *(u16x8*)&Klds[cur ^ 1][kj2][kd]     = kr;
            *(u16x8*)&Vlds[cur ^ 1][vd][vjb]     = vr0;
            *(u16x8*)&Vlds[cur ^ 1][vd][vjb + 8] = vr1;
            if (it + 2 < 9) ldregs(jbase + (it + 2) * 64);
        }

        f32x4 sacc[2][4];
        __builtin_amdgcn_s_setprio(1);
        #pragma unroll
        for (int js = 0; js < 4; ++js) {
            s8v kf = *(const s8v*)&Klds[cur][js * 16 + li][8 * g];
            f32x4 zz = f32x4{0.f, 0.f, 0.f, 0.f};
            sacc[0][js] = __builtin_amdgcn_mfma_f32_16x16x32_bf16(kf, qf[0], zz, 0, 0, 0);
            sacc[1][js] = __builtin_amdgcn_mfma_f32_16x16x32_bf16(kf, qf[1], zz, 0, 0, 0);
        }
        __builtin_amdgcn_s_setprio(0);

        #pragma unroll
        for (int q2 = 0; q2 < 2; ++q2) {
            // local lane max only (no cross-lane reduce on the common path)
            float tm = -1e30f;
            #pragma unroll
            for (int js = 0; js < 4; ++js)
                #pragma unroll
                for (int r = 0; r < 4; ++r) tm = fmaxf(tm, sacc[q2][js][r]);
            if (__any(tm > m_run[q2] + 8.f)) {     // defer-max (T13), ballot-only
                float tmf = tm;
                tmf = fmaxf(tmf, __shfl_xor(tmf, 16, 64));
                tmf = fmaxf(tmf, __shfl_xor(tmf, 32, 64));
                float mnew = fmaxf(m_run[q2], tmf);
                float scl  = fexp2(m_run[q2] - mnew);
                l_run[q2] *= scl;
                #pragma unroll
                for (int dt = 0; dt < 4; ++dt) oacc[q2][dt] *= scl;
                m_run[q2] = mnew;
            }
            float ts = 0.f;
            #pragma unroll
            for (int js = 0; js < 4; ++js)
                #pragma unroll
                for (int r = 0; r < 4; ++r) {
                    float pv = fexp2(sacc[q2][js][r] - m_run[q2]);
                    sacc[q2][js][r] = pv;
                    ts += pv;
                }
            l_run[q2] += ts;                       // per-lane partial sum
        }

        __builtin_amdgcn_s_setprio(1);
        #pragma unroll
        for (int ks = 0; ks < 2; ++ks) {
            s8v pf[2];
            #pragma unroll
            for (int q2 = 0; q2 < 2; ++q2) {
                u32x4 pw;
                pw[0] = cvtpk(sacc[q2][2 * ks][0],     sacc[q2][2 * ks][1]);
                pw[1] = cvtpk(sacc[q2][2 * ks][2],     sacc[q2][2 * ks][3]);
                pw[2] = cvtpk(sacc[q2][2 * ks + 1][0], sacc[q2][2 * ks + 1][1]);
                pw[3] = cvtpk(sacc[q2][2 * ks + 1][2], sacc[q2][2 * ks + 1][3]);
                pf[q2] = __builtin_bit_cast(s8v, pw);
            }
            #pragma unroll
            for (int dt = 0; dt < 4; ++dt) {
                int d = dt * 16 + li;
                s4v lo = *(const s4v*)&Vlds[cur][d][32 * ks + 4 * g];
                s4v hi = *(const s4v*)&Vlds[cur][d][32 * ks + 16 + 4 * g];
                s8v vf = __builtin_shufflevector(lo, hi, 0, 1, 2, 3, 4, 5, 6, 7);
                oacc[0][dt] = __builtin_amdgcn_mfma_f32_16x16x32_bf16(vf, pf[0], oacc[0][dt], 0, 0, 0);
                oacc[1][dt] = __builtin_amdgcn_mfma_f32_16x16x32_bf16(vf, pf[1], oacc[1][dt], 0, 0, 0);
            }
        }
        __builtin_amdgcn_s_setprio(0);

        if (it + 1 < 9) bar_lgkm();
        cur ^= 1;
    }

    const long cb = (long)(z * 16 + bh);
    #pragma unroll
    for (int q2 = 0; q2 < 2; ++q2) {
        const int i = q2 ? ib : ia;
        float lt = l_run[q2];
        lt += __shfl_xor(lt, 16, 64);
        lt += __shfl_xor(lt, 32, 64);
        #pragma unroll
        for (int dt = 0; dt < 4; ++dt)
            #pragma unroll
            for (int r = 0; r < 4; ++r)
                Opart[(cb * 64 + dt * 16 + 4 * g + r) * N + i] = (u16)f2bf(oacc[q2][dt][r]);
        if (g == 0) {
            mpart[cb * N + i] = m_run[q2];
            lpart[cb * N + i] = lt;
        }
    }
}

// ---------------------------------------------------------------------------
// Combine split-j partials (x4) + fused depthwise-3x3 PE from qkvT
// (vectorized, line-coherent). Writes attnT [b][n][256] (bf16) for proj.
// ---------------------------------------------------------------------------
__global__ __launch_bounds__(256) void attn_combine(
    const u16* __restrict__ Opart, const float* __restrict__ mpart,
    const float* __restrict__ lpart, const u16* __restrict__ qkvT,
    const float* __restrict__ pw, const float* __restrict__ ps,
    const float* __restrict__ pb, u16* __restrict__ attnT)
{
    const int N = N_SP;
    const int i0 = blockIdx.x * 64;
    const int bh = blockIdx.y;
    const int b = bh >> 2, h = bh & 3;
    const int t = threadIdx.x;
    const int il = t & 63, dq = t >> 6;
    const int d0 = dq * 16;
    const int i = i0 + il;

    float mm[4], ll[4];
    #pragma unroll
    for (int c = 0; c < 4; ++c) {
        mm[c] = mpart[((long)(c * 16 + bh)) * N + i];
        ll[c] = lpart[((long)(c * 16 + bh)) * N + i];
    }
    float ms = fmaxf(fmaxf(mm[0], mm[1]), fmaxf(mm[2], mm[3]));
    float wc[4], lsum = 0.f;
    #pragma unroll
    for (int c = 0; c < 4; ++c) {
        wc[c] = fexp2(mm[c] - ms);
        lsum += wc[c] * ll[c];
    }
    float inv = frcp(lsum);

    const int y = i / HW, x = i - (i / HW) * HW;
    const u16* vT = qkvT + (long)b * N * 512 + h * 128 + 64 + d0;
    float pe[16];
    #pragma unroll
    for (int dd = 0; dd < 16; ++dd) pe[dd] = 0.f;
    #pragma unroll
    for (int dy = -1; dy <= 1; ++dy) {
        int yy = y + dy;
        if (yy < 0 || yy >= HW) continue;
        #pragma unroll
        for (int dx = -1; dx <= 1; ++dx) {
            int xx = x + dx;
            if (xx < 0 || xx >= HW) continue;
            const int k = (dy + 1) * 3 + (dx + 1);
            const u16* pvt = vT + (long)(yy * HW + xx) * 512;
            u16x8 a0 = *(const u16x8*)pvt;
            u16x8 a1 = *(const u16x8*)(pvt + 8);
            #pragma unroll
            for (int dd = 0; dd < 8; ++dd) {
                pe[dd]     += pw[(h * 64 + d0 + dd) * 9 + k]     * bf2f((u16)a0[dd]);
                pe[8 + dd] += pw[(h * 64 + d0 + 8 + dd) * 9 + k] * bf2f((u16)a1[dd]);
            }
        }
    }

    u16 ob[16];
    #pragma unroll
    for (int dd = 0; dd < 16; ++dd) {
        const int d = d0 + dd;
        const int cg = h * 64 + d;
        float o = 0.f;
        #pragma unroll
        for (int c = 0; c < 4; ++c)
            o += wc[c] * bf2f(Opart[((long)(c * 16 + bh) * 64 + d) * N + i]);
        o = o * inv + pe[dd] * ps[cg] + pb[cg];
        ob[dd] = (u16)f2bf(o);
    }
    u16* dst = attnT + ((long)b * N + i) * 256 + h * 64 + d0;
    *(u16x8*)dst       = *(u16x8*)&ob[0];
    *(u16x8*)(dst + 8) = *(u16x8*)&ob[8];
}

// ---------------------------------------------------------------------------
extern "C" void kernel_launch(void* const* d_in, const int* in_sizes, int n_in,
                              void* d_out, int out_size, void* d_ws, size_t ws_size,
                              hipStream_t stream)
{
    const long N = N_SP;
    const float* x      = (const float*)d_in[0];
    const float* cv1_w  = (const float*)d_in[1];
    const float* cv1_s  = (const float*)d_in[2];
    const float* cv1_b  = (const float*)d_in[3];
    const float* qkv_w  = (const float*)d_in[4];
    const float* qkv_s  = (const float*)d_in[5];
    const float* qkv_b  = (const float*)d_in[6];
    const float* pe_w   = (const float*)d_in[7];
    const float* pe_s   = (const float*)d_in[8];
    const float* pe_b   = (const float*)d_in[9];
    const float* proj_w = (const float*)d_in[10];
    const float* proj_s = (const float*)d_in[11];
    const float* proj_b = (const float*)d_in[12];
    const float* ffn1_w = (const float*)d_in[13];
    const float* ffn1_s = (const float*)d_in[14];
    const float* ffn1_b = (const float*)d_in[15];
    const float* ffn2_w = (const float*)d_in[16];
    const float* ffn2_s = (const float*)d_in[17];
    const float* ffn2_b = (const float*)d_in[18];
    const float* cv2_w  = (const float*)d_in[19];
    const float* cv2_s  = (const float*)d_in[20];
    const float* cv2_b  = (const float*)d_in[21];
    float* out = (float*)d_out;

    u16* ws = (u16*)d_ws;
    u16* xT      = ws;                       // [4][2304][512]
    u16* abT     = xT      + 4L * N * 512;   // [4][2304][512]
    u16* qkvb    = abT     + 4L * N * 512;   // [4][512][2304]
    u16* qkvT    = qkvb    + 4L * N * 512;   // [4][2304][512]
    u16* attnT   = qkvT    + 4L * N * 512;   // [4][2304][256]
    u16* bb2T    = attnT   + 4L * N * 256;   // [4][2304][256]
    u16* fT      = bb2T    + 4L * N * 256;   // [4][2304][512]
    u16* bb3T    = fT      + 4L * N * 512;   // [4][2304][256]
    u16* w_cv1   = bb3T    + 4L * N * 256;   // 512*512
    u16* w_qkv   = w_cv1   + 512L * 512;
    u16* w_proj  = w_qkv   + 512L * 256;
    u16* w_ffn1  = w_proj  + 256L * 256;
    u16* w_ffn2  = w_ffn1  + 512L * 256;
    u16* w_cv2   = w_ffn2  + 256L * 512;
    u16* Opart   = w_cv2   + 512L * 512;     // [4][16][64][2304] bf16
    float* mpart = (float*)(Opart + 4L * 16 * 64 * N);   // [4][16][2304]
    float* lpart = mpart + 4L * 16 * N;

    dim3 blk(256);
    const int BIGK = 1 << 28;

    // 0. merged weight-convert + x-transpose
    prep<<<2112, blk, 0, stream>>>(x, xT,
        cv1_w, qkv_w, proj_w, ffn1_w, ffn2_w, cv2_w,
        w_cv1, w_qkv, w_proj, w_ffn1, w_ffn2, w_cv2);

    // 1. abT = silu(cv1(x))^T   (128-row tile, 3-buf counted vmcnt)
    mfma_gemm_big<8, 0><<<576, blk, 0, stream>>>(
        xT, nullptr, BIGK, 512, 0, 512, w_cv1, cv1_s, cv1_b,
        nullptr, 0, abT, nullptr, 512, 512, 1);

    // 2. qkvb normal [b][512][N]  +  qkvT transposed [b][N][512]
    mfma_gemm_big<8, 3><<<576, blk, 0, stream>>>(
        abT + 256, nullptr, BIGK, 512, 0, 256, w_qkv, qkv_s, qkv_b,
        nullptr, 0, qkvb, qkvT, 0, 512, 0);

    // 3. attention partials (split-j x4, 128 queries/block)
    attn_mfma<<<1152, blk, 0, stream>>>(qkvb, qkvT, Opart, mpart, lpart);

    // 4. combine + fused PE -> attnT [b][n][256]
    attn_combine<<<dim3(36, 16), blk, 0, stream>>>(
        Opart, mpart, lpart, qkvT, pe_w, pe_s, pe_b, attnT);

    // 5. bb2T = bb^T + proj(attn)^T   (64-tile kernel, single-round)
    mfma_gemm<4, 0><<<576, blk, 0, stream>>>(
        attnT, nullptr, BIGK, 256, 0, 256, w_proj, proj_s, proj_b,
        abT + 256, 512, bb2T, nullptr, 256, 256, 0);

    // 6. fT = silu(ffn1(bb2))^T   (128-row tile, 3-buf counted vmcnt)
    mfma_gemm_big<8, 0><<<576, blk, 0, stream>>>(
        bb2T, nullptr, BIGK, 256, 0, 256, w_ffn1, ffn1_s, ffn1_b,
        nullptr, 0, fT, nullptr, 512, 512, 1);

    // 7. bb3T = bb2T + ffn2(f)^T   (64-tile kernel)
    mfma_gemm<4, 0><<<576, blk, 0, stream>>>(
        fT, nullptr, BIGK, 512, 0, 512, w_ffn2, ffn2_s, ffn2_b,
        bb2T, 256, bb3T, nullptr, 256, 256, 0);

    // 8. out = silu(cv2(concat(a, bb3)))  fp32 normal [b][512][N]  (128-row)
    mfma_gemm_big<8, 2><<<576, blk, 0, stream>>>(
        abT, bb3T, 256, 512, 256, 512, w_cv2, cv2_s, cv2_b,
        nullptr, 0, out, nullptr, 0, 512, 1);
}

// Round 19
// 122.362 us; speedup vs baseline: 1.1304x; 1.1304x over previous
//
#include <hip/hip_runtime.h>
#include <math.h>

#define N_SP 2304   // 48*48 spatial
#define HW 48

typedef unsigned short u16;
typedef short s8v  __attribute__((ext_vector_type(8)));   // bf16x8 (MFMA operand)
typedef short s4v  __attribute__((ext_vector_type(4)));   // bf16x4
typedef u16   u16x8 __attribute__((ext_vector_type(8)));
typedef float f32x4 __attribute__((ext_vector_type(4)));
typedef unsigned u32x4 __attribute__((ext_vector_type(4)));

__device__ __forceinline__ short f2bf(float x) {
    unsigned u = __float_as_uint(x);
    u += 0x7FFFu + ((u >> 16) & 1u);
    return (short)(u >> 16);
}
__device__ __forceinline__ float bf2f(u16 u) {
    return __uint_as_float((unsigned)u << 16);
}
__device__ __forceinline__ float fexp2(float x) { return __builtin_amdgcn_exp2f(x); }
__device__ __forceinline__ float frcp(float x)  { return __builtin_amdgcn_rcpf(x); }
__device__ __forceinline__ float fsilu(float v) {
    return v * frcp(1.f + fexp2(-1.4426950408889634f * v));
}
__device__ __forceinline__ unsigned cvtpk(float lo, float hi) {  // 2xf32 -> packed bf16
    unsigned r;
    asm("v_cvt_pk_bf16_f32 %0, %1, %2" : "=v"(r) : "v"(lo), "v"(hi));
    return r;
}
__device__ __forceinline__ void gload16(const void* g, void* l) {
    __builtin_amdgcn_global_load_lds(
        (const __attribute__((address_space(1))) void*)g,
        (__attribute__((address_space(3))) void*)l, 16, 0, 0);
}
// raw barrier WITHOUT vmcnt drain (keeps prefetch loads in flight)
__device__ __forceinline__ void bar_lgkm() {
    asm volatile("s_waitcnt lgkmcnt(0)" ::: "memory");
    __builtin_amdgcn_s_barrier();
}

// ---------------------------------------------------------------------------
// prep: merged weight fp32->bf16 convert (blocks 0..959) and x transpose
// (blocks 960..2111): x [b][512][2304] fp32 -> xT [b][2304][512] bf16.
// ---------------------------------------------------------------------------
__global__ __launch_bounds__(256) void prep(
    const float* __restrict__ X, u16* __restrict__ XT,
    const float* __restrict__ s0, const float* __restrict__ s1,
    const float* __restrict__ s2, const float* __restrict__ s3,
    const float* __restrict__ s4, const float* __restrict__ s5,
    u16* __restrict__ d0, u16* __restrict__ d1, u16* __restrict__ d2,
    u16* __restrict__ d3, u16* __restrict__ d4, u16* __restrict__ d5)
{
    __shared__ float tile[64][65];
    const int t = threadIdx.x;
    if (blockIdx.x < 960) {
        int id = blockIdx.x * 256 + t;   // float4 index
        const int c0 = 65536, c1 = c0 + 32768, c2 = c1 + 16384,
                  c3 = c2 + 32768, c4 = c3 + 32768, c5 = c4 + 65536;
        if (id >= c5) return;
        const float* s; u16* d; int off;
        if      (id < c0) { s = s0; d = d0; off = id; }
        else if (id < c1) { s = s1; d = d1; off = id - c0; }
        else if (id < c2) { s = s2; d = d2; off = id - c1; }
        else if (id < c3) { s = s3; d = d3; off = id - c2; }
        else if (id < c4) { s = s4; d = d4; off = id - c3; }
        else              { s = s5; d = d5; off = id - c4; }
        float4 v = ((const float4*)s)[off];
        s4v p; p[0] = f2bf(v.x); p[1] = f2bf(v.y); p[2] = f2bf(v.z); p[3] = f2bf(v.w);
        ((s4v*)d)[off] = p;
        return;
    }
    // transpose part: 1152 blocks = 36 x 8 x 4
    const int bid = blockIdx.x - 960;
    const int n0 = (bid % 36) * 64, c0 = ((bid / 36) & 7) * 64, b = bid / 288;
    const float* src = X + (long)b * 512 * N_SP;
    u16* dst = XT + (long)b * N_SP * 512;
    #pragma unroll
    for (int it = 0; it < 16; ++it) {
        int id = t + 256 * it;
        int cl = id >> 6, nl = id & 63;
        tile[cl][nl] = src[(long)(c0 + cl) * N_SP + n0 + nl];
    }
    __syncthreads();
    #pragma unroll
    for (int it = 0; it < 16; ++it) {
        int id = t + 256 * it;
        int nl = id >> 6, cl = id & 63;
        dst[(long)(n0 + nl) * 512 + c0 + cl] = f2bf(tile[cl][nl]);
    }
}

// ---------------------------------------------------------------------------
// Shared GEMM epilogue (scale/bias/silu/residual + output modes).
// ---------------------------------------------------------------------------
template <int OMODE>
__device__ __forceinline__ void gemm_epilogue(
    float y[4], int nb, int nib, int o, int b_blk, int Mtot,
    const u16* Res, int sR, void* OutP, u16* OutT, int sO)
{
    if (Res) {
        #pragma unroll
        for (int r = 0; r < 4; ++r)
            y[r] += bf2f(Res[(long)(nb + r) * sR + o]);
    }
    if (OMODE == 0) {
        u16* O = (u16*)OutP;
        #pragma unroll
        for (int r = 0; r < 4; ++r)
            O[(long)(nb + r) * sO + o] = (u16)f2bf(y[r]);
    } else if (OMODE == 1 || OMODE == 3) {
        u16* O = (u16*)OutP + (long)b_blk * Mtot * N_SP + (long)o * N_SP + nib;
        s4v pk;
        #pragma unroll
        for (int r = 0; r < 4; ++r) pk[r] = f2bf(y[r]);
        *(s4v*)O = pk;
        if (OMODE == 3) {
            #pragma unroll
            for (int r = 0; r < 4; ++r)
                OutT[(long)(nb + r) * 512 + o] = (u16)f2bf(y[r]);
        }
    } else {
        float* O = (float*)OutP + (long)b_blk * Mtot * N_SP + (long)o * N_SP + nib;
        *(float4*)O = make_float4(y[0], y[1], y[2], y[3]);
    }
}

// ---------------------------------------------------------------------------
// MFMA GEMM (64x64 tile, BK=64, 3-buffer counted vmcnt(4)) — used for the
// M=256 GEMMs (proj, ffn2; grid 576 = 2.25/CU, single-round).
// XCD-clustered 1D grid.
// ---------------------------------------------------------------------------
template <int NO, int OMODE>
__global__ __launch_bounds__(256) void mfma_gemm(
    const u16* __restrict__ A1, const u16* __restrict__ A2, int K1,
    int sA1, int sA2, int K,
    const u16* __restrict__ W,
    const float* __restrict__ S, const float* __restrict__ Bi,
    const u16* __restrict__ Res, int sR,
    void* __restrict__ OutP, u16* __restrict__ OutT, int sO, int Mtot,
    int act)
{
    __shared__ u16 Al[3][64][64];
    __shared__ u16 Bl[3][64][64];
    const int t  = threadIdx.x;
    const int p = blockIdx.x;
    const int cx = p & 7, q = p >> 3;
    const int n0 = (cx * 18 + q / NO) * 64;
    const int o0 = (q % NO) * 64;
    const int lane = t & 63, w = t >> 6;
    const int wn = (w & 1) * 32, wo = (w >> 1) * 32;
    const int li = lane & 15, g = lane >> 4;

    const int b_blk = n0 / N_SP;
    const int n_in0 = n0 - b_blk * N_SP;

    f32x4 acc[2][2];
    #pragma unroll
    for (int fm = 0; fm < 2; ++fm)
        #pragma unroll
        for (int fn = 0; fn < 2; ++fn) acc[fm][fn] = f32x4{0.f, 0.f, 0.f, 0.f};

    auto issue = [&](int buf, int k0) {
        #pragma unroll
        for (int qq = 0; qq < 2; ++qq) {
            int c = t + qq * 256;
            int row = c >> 3;
            int col = ((c & 7) ^ (row & 7)) * 8;   // inverse-swizzled source
            int kk = k0 + col;
            const u16* ga = (kk < K1) ? (A1 + (long)(n0 + row) * sA1 + kk)
                                      : (A2 + (long)(n0 + row) * sA2 + (kk - K1));
            gload16(ga, (u16*)Al[buf] + (qq * 256 + w * 64) * 8);
            gload16(W + (long)(o0 + row) * K + k0 + col,
                    (u16*)Bl[buf] + (qq * 256 + w * 64) * 8);
        }
    };

    const int NK = K >> 6;
    issue(0, 0);
    if (NK > 1) issue(1, 64);

    for (int ks = 0; ks < NK; ++ks) {
        if (ks + 1 < NK) asm volatile("s_waitcnt vmcnt(4)" ::: "memory");
        else             asm volatile("s_waitcnt vmcnt(0)" ::: "memory");
        __builtin_amdgcn_s_barrier();
        if (ks + 2 < NK) issue((ks + 2) % 3, (ks + 2) << 6);
        const int cur = ks % 3;
        #pragma unroll
        for (int k2 = 0; k2 < 2; ++k2) {
            s8v af[2], bfv[2];
            #pragma unroll
            for (int fm = 0; fm < 2; ++fm) {
                int row = wn + fm * 16 + li;
                af[fm] = *(const s8v*)&Al[cur][row][((g + 4 * k2) ^ (li & 7)) * 8];
            }
            #pragma unroll
            for (int fn = 0; fn < 2; ++fn) {
                int row = wo + fn * 16 + li;
                bfv[fn] = *(const s8v*)&Bl[cur][row][((g + 4 * k2) ^ (li & 7)) * 8];
            }
            #pragma unroll
            for (int fm = 0; fm < 2; ++fm)
                #pragma unroll
                for (int fn = 0; fn < 2; ++fn)
                    acc[fm][fn] = __builtin_amdgcn_mfma_f32_16x16x32_bf16(
                        af[fm], bfv[fn], acc[fm][fn], 0, 0, 0);
        }
    }

    #pragma unroll
    for (int fn = 0; fn < 2; ++fn) {
        const int o = o0 + wo + fn * 16 + li;
        const float sc2 = S[o], bi = Bi[o];
        #pragma unroll
        for (int fm = 0; fm < 2; ++fm) {
            const int nb  = n0 + wn + fm * 16 + 4 * g;
            const int nib = n_in0 + wn + fm * 16 + 4 * g;
            float y[4];
            #pragma unroll
            for (int r = 0; r < 4; ++r) {
                float v = acc[fm][fn][r] * sc2 + bi;
                if (act) v = fsilu(v);
                y[r] = v;
            }
            gemm_epilogue<OMODE>(y, nb, nib, o, b_blk, Mtot, Res, sR, OutP, OutT, sO);
        }
    }
}

// ---------------------------------------------------------------------------
// BIG MFMA GEMM (128n x 64o tile, BK=64, 2-buffer 2-phase) — M=512 GEMMs.
// 48 KB LDS -> 3 blocks/CU, grid 576 single-round (R17's 3-buffer 72 KB
// dropped to 2 blocks/CU -> TWO dispatch rounds, regressed; single-round
// occupancy outranks counted-vmcnt at this size).
// af[4] x bfv[2] = 16 MFMA / 12 ds_reads.
// ---------------------------------------------------------------------------
template <int NO, int OMODE>
__global__ __launch_bounds__(256) void mfma_gemm_big(
    const u16* __restrict__ A1, const u16* __restrict__ A2, int K1,
    int sA1, int sA2, int K,
    const u16* __restrict__ W,
    const float* __restrict__ S, const float* __restrict__ Bi,
    const u16* __restrict__ Res, int sR,
    void* __restrict__ OutP, u16* __restrict__ OutT, int sO, int Mtot,
    int act)
{
    __shared__ u16 Al[2][128][64];
    __shared__ u16 Bl[2][64][64];
    const int t  = threadIdx.x;
    const int p = blockIdx.x;
    const int cx = p & 7, q = p >> 3;
    const int n0 = (cx * 9 + q / NO) * 128;   // 72 n-tiles = 8 XCD cls x 9
    const int o0 = (q % NO) * 64;
    const int lane = t & 63, w = t >> 6;
    const int wn = (w & 1) * 64, wo = (w >> 1) * 32;
    const int li = lane & 15, g = lane >> 4;

    const int b_blk = n0 / N_SP;              // 2304 % 128 == 0
    const int n_in0 = n0 - b_blk * N_SP;

    f32x4 acc[4][2];
    #pragma unroll
    for (int fm = 0; fm < 4; ++fm)
        #pragma unroll
        for (int fn = 0; fn < 2; ++fn) acc[fm][fn] = f32x4{0.f, 0.f, 0.f, 0.f};

    auto issue = [&](int buf, int k0) {
        #pragma unroll
        for (int qq = 0; qq < 4; ++qq) {
            int c = t + qq * 256;
            int row = c >> 3;
            int col = ((c & 7) ^ (row & 7)) * 8;   // inverse-swizzled source
            int kk = k0 + col;
            const u16* ga = (kk < K1) ? (A1 + (long)(n0 + row) * sA1 + kk)
                                      : (A2 + (long)(n0 + row) * sA2 + (kk - K1));
            gload16(ga, (u16*)Al[buf] + (qq * 256 + w * 64) * 8);
        }
        #pragma unroll
        for (int qq = 0; qq < 2; ++qq) {
            int c = t + qq * 256;
            int row = c >> 3;
            int col = ((c & 7) ^ (row & 7)) * 8;
            gload16(W + (long)(o0 + row) * K + k0 + col,
                    (u16*)Bl[buf] + (qq * 256 + w * 64) * 8);
        }
    };

    const int NK = K >> 6;
    issue(0, 0);
    asm volatile("s_waitcnt vmcnt(0)" ::: "memory");
    __builtin_amdgcn_s_barrier();

    int cur = 0;
    for (int ks = 0; ks < NK; ++ks) {
        if (ks + 1 < NK) issue(cur ^ 1, (ks + 1) << 6);   // in flight over compute
        #pragma unroll
        for (int k2 = 0; k2 < 2; ++k2) {
            s8v af[4], bfv[2];
            #pragma unroll
            for (int fm = 0; fm < 4; ++fm) {
                int row = wn + fm * 16 + li;               // row&7 == li&7
                af[fm] = *(const s8v*)&Al[cur][row][((g + 4 * k2) ^ (li & 7)) * 8];
            }
            #pragma unroll
            for (int fn = 0; fn < 2; ++fn) {
                int row = wo + fn * 16 + li;
                bfv[fn] = *(const s8v*)&Bl[cur][row][((g + 4 * k2) ^ (li & 7)) * 8];
            }
            #pragma unroll
            for (int fm = 0; fm < 4; ++fm)
                #pragma unroll
                for (int fn = 0; fn < 2; ++fn)
                    acc[fm][fn] = __builtin_amdgcn_mfma_f32_16x16x32_bf16(
                        af[fm], bfv[fn], acc[fm][fn], 0, 0, 0);
        }
        if (ks + 1 < NK) {
            asm volatile("s_waitcnt vmcnt(0)" ::: "memory");
            __builtin_amdgcn_s_barrier();
        }
        cur ^= 1;
    }

    #pragma unroll
    for (int fn = 0; fn < 2; ++fn) {
        const int o = o0 + wo + fn * 16 + li;
        const float sc2 = S[o], bi = Bi[o];
        #pragma unroll
        for (int fm = 0; fm < 4; ++fm) {
            const int nb  = n0 + wn + fm * 16 + 4 * g;
            const int nib = n_in0 + wn + fm * 16 + 4 * g;
            float y[4];
            #pragma unroll
            for (int r = 0; r < 4; ++r) {
                float v = acc[fm][fn][r] * sc2 + bi;
                if (act) v = fsilu(v);
                y[r] = v;
            }
            gemm_epilogue<OMODE>(y, nb, nib, o, b_blk, Mtot, Res, sR, OutP, OutT, sO);
        }
    }
}

// ---------------------------------------------------------------------------
// MFMA flash attention, split-j x4, 2 q-frags/wave (128 queries/block).
// Q/K from qkvT (b128 loads), V from qkvb. Double-buffered LDS, one raw
// barrier per tile, XCD-clustered grid, setprio around MFMA clusters.
// R16 shuffle-free softmax: local-max + __any ballot defer check; l kept as
// per-lane partial, reduced once in the epilogue.
// ---------------------------------------------------------------------------
__global__ __launch_bounds__(256) void attn_mfma(const u16* __restrict__ qkv,
    const u16* __restrict__ qkvT,
    u16* __restrict__ Opart, float* __restrict__ mpart, float* __restrict__ lpart)
{
    const int N = N_SP;
    __shared__ u16 Klds[2][64][40];   // [j][d]
    __shared__ u16 Vlds[2][64][72];   // [d][j]

    const int p = blockIdx.x;
    const int cx = p & 7, q = p >> 3;
    const int i0 = (q % 18) * 128;
    const int bhz = cx + 8 * (q / 18);     // 0..63
    const int bh = bhz & 15, z = bhz >> 4; // z = j-chunk 0..3
    const int b = bh >> 2, h = bh & 3;
    const int t = threadIdx.x;
    const int w = t >> 6;
    const int lane = t & 63;
    const int li = lane & 15;
    const int g  = lane >> 4;
    const float qscale = 0.17677669529663687f * 1.4426950408889634f;

    const u16* qp  = qkv  + ((long)b * 512 + (long)h * 128) * N;
    const u16* vp  = qp + 64L * N;
    const u16* qTp = qkvT + (long)b * N * 512 + h * 128;

    const int ia = i0 + w * 16 + li;     // q-frag 0
    const int ib = ia + 64;              // q-frag 1

    s8v qf[2];
    {
        s8v qa = *(const s8v*)(qTp + (long)ia * 512 + 8 * g);
        s8v qb = *(const s8v*)(qTp + (long)ib * 512 + 8 * g);
        #pragma unroll
        for (int r = 0; r < 8; ++r) {
            qf[0][r] = f2bf(bf2f((u16)qa[r]) * qscale);
            qf[1][r] = f2bf(bf2f((u16)qb[r]) * qscale);
        }
    }

    f32x4 oacc[2][4];
    #pragma unroll
    for (int q2 = 0; q2 < 2; ++q2)
        #pragma unroll
        for (int dt = 0; dt < 4; ++dt) oacc[q2][dt] = f32x4{0.f, 0.f, 0.f, 0.f};
    float m_run[2] = {-1e30f, -1e30f}, l_run[2] = {0.f, 0.f};  // l: per-lane partial

    const int kj2 = t & 63;            // j within tile (K staging)
    const int kd  = (t >> 6) * 8;      // 8-d chunk
    const int vd  = t >> 2;            // 0..63
    const int vjb = (t & 3) * 16;      // 0..48

    const int jbase = z * 576;
    u16x8 kr, vr0, vr1;
    auto ldregs = [&](int j0) {
        kr  = *(const u16x8*)(qTp + (long)(j0 + kj2) * 512 + 32 + kd);
        vr0 = *(const u16x8*)(vp + (long)vd * N + j0 + vjb);
        vr1 = *(const u16x8*)(vp + (long)vd * N + j0 + vjb + 8);
    };

    ldregs(jbase);
    *(u16x8*)&Klds[0][kj2][kd]     = kr;
    *(u16x8*)&Vlds[0][vd][vjb]     = vr0;
    *(u16x8*)&Vlds[0][vd][vjb + 8] = vr1;
    ldregs(jbase + 64);
    bar_lgkm();

    int cur = 0;
    for (int it = 0; it < 9; ++it) {
        if (it + 1 < 9) {
            *(u16x8*)&Klds[cur ^ 1][kj2][kd]     = kr;
            *(u16x8*)&Vlds[cur ^ 1][vd][vjb]     = vr0;
            *(u16x8*)&Vlds[cur ^ 1][vd][vjb + 8] = vr1;
            if (it + 2 < 9) ldregs(jbase + (it + 2) * 64);
        }

        f32x4 sacc[2][4];
        __builtin_amdgcn_s_setprio(1);
        #pragma unroll
        for (int js = 0; js < 4; ++js) {
            s8v kf = *(const s8v*)&Klds[cur][js * 16 + li][8 * g];
            f32x4 zz = f32x4{0.f, 0.f, 0.f, 0.f};
            sacc[0][js] = __builtin_amdgcn_mfma_f32_16x16x32_bf16(kf, qf[0], zz, 0, 0, 0);
            sacc[1][js] = __builtin_amdgcn_mfma_f32_16x16x32_bf16(kf, qf[1], zz, 0, 0, 0);
        }
        __builtin_amdgcn_s_setprio(0);

        #pragma unroll
        for (int q2 = 0; q2 < 2; ++q2) {
            // local lane max only (no cross-lane reduce on the common path)
            float tm = -1e30f;
            #pragma unroll
            for (int js = 0; js < 4; ++js)
                #pragma unroll
                for (int r = 0; r < 4; ++r) tm = fmaxf(tm, sacc[q2][js][r]);
            if (__any(tm > m_run[q2] + 8.f)) {     // defer-max (T13), ballot-only
                float tmf = tm;
                tmf = fmaxf(tmf, __shfl_xor(tmf, 16, 64));
                tmf = fmaxf(tmf, __shfl_xor(tmf, 32, 64));
                float mnew = fmaxf(m_run[q2], tmf);
                float scl  = fexp2(m_run[q2] - mnew);
                l_run[q2] *= scl;
                #pragma unroll
                for (int dt = 0; dt < 4; ++dt) oacc[q2][dt] *= scl;
                m_run[q2] = mnew;
            }
            float ts = 0.f;
            #pragma unroll
            for (int js = 0; js < 4; ++js)
                #pragma unroll
                for (int r = 0; r < 4; ++r) {
                    float pv = fexp2(sacc[q2][js][r] - m_run[q2]);
                    sacc[q2][js][r] = pv;
                    ts += pv;
                }
            l_run[q2] += ts;                       // per-lane partial sum
        }

        __builtin_amdgcn_s_setprio(1);
        #pragma unroll
        for (int ks = 0; ks < 2; ++ks) {
            s8v pf[2];
            #pragma unroll
            for (int q2 = 0; q2 < 2; ++q2) {
                u32x4 pw;
                pw[0] = cvtpk(sacc[q2][2 * ks][0],     sacc[q2][2 * ks][1]);
                pw[1] = cvtpk(sacc[q2][2 * ks][2],     sacc[q2][2 * ks][3]);
                pw[2] = cvtpk(sacc[q2][2 * ks + 1][0], sacc[q2][2 * ks + 1][1]);
                pw[3] = cvtpk(sacc[q2][2 * ks + 1][2], sacc[q2][2 * ks + 1][3]);
                pf[q2] = __builtin_bit_cast(s8v, pw);
            }
            #pragma unroll
            for (int dt = 0; dt < 4; ++dt) {
                int d = dt * 16 + li;
                s4v lo = *(const s4v*)&Vlds[cur][d][32 * ks + 4 * g];
                s4v hi = *(const s4v*)&Vlds[cur][d][32 * ks + 16 + 4 * g];
                s8v vf = __builtin_shufflevector(lo, hi, 0, 1, 2, 3, 4, 5, 6, 7);
                oacc[0][dt] = __builtin_amdgcn_mfma_f32_16x16x32_bf16(vf, pf[0], oacc[0][dt], 0, 0, 0);
                oacc[1][dt] = __builtin_amdgcn_mfma_f32_16x16x32_bf16(vf, pf[1], oacc[1][dt], 0, 0, 0);
            }
        }
        __builtin_amdgcn_s_setprio(0);

        if (it + 1 < 9) bar_lgkm();
        cur ^= 1;
    }

    const long cb = (long)(z * 16 + bh);
    #pragma unroll
    for (int q2 = 0; q2 < 2; ++q2) {
        const int i = q2 ? ib : ia;
        float lt = l_run[q2];
        lt += __shfl_xor(lt, 16, 64);
        lt += __shfl_xor(lt, 32, 64);
        #pragma unroll
        for (int dt = 0; dt < 4; ++dt)
            #pragma unroll
            for (int r = 0; r < 4; ++r)
                Opart[(cb * 64 + dt * 16 + 4 * g + r) * N + i] = (u16)f2bf(oacc[q2][dt][r]);
        if (g == 0) {
            mpart[cb * N + i] = m_run[q2];
            lpart[cb * N + i] = lt;
        }
    }
}

// ---------------------------------------------------------------------------
// Combine split-j partials (x4) + fused depthwise-3x3 PE from qkvT
// (vectorized, line-coherent). Writes attnT [b][n][256] (bf16) for proj.
// ---------------------------------------------------------------------------
__global__ __launch_bounds__(256) void attn_combine(
    const u16* __restrict__ Opart, const float* __restrict__ mpart,
    const float* __restrict__ lpart, const u16* __restrict__ qkvT,
    const float* __restrict__ pw, const float* __restrict__ ps,
    const float* __restrict__ pb, u16* __restrict__ attnT)
{
    const int N = N_SP;
    const int i0 = blockIdx.x * 64;
    const int bh = blockIdx.y;
    const int b = bh >> 2, h = bh & 3;
    const int t = threadIdx.x;
    const int il = t & 63, dq = t >> 6;
    const int d0 = dq * 16;
    const int i = i0 + il;

    float mm[4], ll[4];
    #pragma unroll
    for (int c = 0; c < 4; ++c) {
        mm[c] = mpart[((long)(c * 16 + bh)) * N + i];
        ll[c] = lpart[((long)(c * 16 + bh)) * N + i];
    }
    float ms = fmaxf(fmaxf(mm[0], mm[1]), fmaxf(mm[2], mm[3]));
    float wc[4], lsum = 0.f;
    #pragma unroll
    for (int c = 0; c < 4; ++c) {
        wc[c] = fexp2(mm[c] - ms);
        lsum += wc[c] * ll[c];
    }
    float inv = frcp(lsum);

    const int y = i / HW, x = i - (i / HW) * HW;
    const u16* vT = qkvT + (long)b * N * 512 + h * 128 + 64 + d0;
    float pe[16];
    #pragma unroll
    for (int dd = 0; dd < 16; ++dd) pe[dd] = 0.f;
    #pragma unroll
    for (int dy = -1; dy <= 1; ++dy) {
        int yy = y + dy;
        if (yy < 0 || yy >= HW) continue;
        #pragma unroll
        for (int dx = -1; dx <= 1; ++dx) {
            int xx = x + dx;
            if (xx < 0 || xx >= HW) continue;
            const int k = (dy + 1) * 3 + (dx + 1);
            const u16* pvt = vT + (long)(yy * HW + xx) * 512;
            u16x8 a0 = *(const u16x8*)pvt;
            u16x8 a1 = *(const u16x8*)(pvt + 8);
            #pragma unroll
            for (int dd = 0; dd < 8; ++dd) {
                pe[dd]     += pw[(h * 64 + d0 + dd) * 9 + k]     * bf2f((u16)a0[dd]);
                pe[8 + dd] += pw[(h * 64 + d0 + 8 + dd) * 9 + k] * bf2f((u16)a1[dd]);
            }
        }
    }

    u16 ob[16];
    #pragma unroll
    for (int dd = 0; dd < 16; ++dd) {
        const int d = d0 + dd;
        const int cg = h * 64 + d;
        float o = 0.f;
        #pragma unroll
        for (int c = 0; c < 4; ++c)
            o += wc[c] * bf2f(Opart[((long)(c * 16 + bh) * 64 + d) * N + i]);
        o = o * inv + pe[dd] * ps[cg] + pb[cg];
        ob[dd] = (u16)f2bf(o);
    }
    u16* dst = attnT + ((long)b * N + i) * 256 + h * 64 + d0;
    *(u16x8*)dst       = *(u16x8*)&ob[0];
    *(u16x8*)(dst + 8) = *(u16x8*)&ob[8];
}

// ---------------------------------------------------------------------------
extern "C" void kernel_launch(void* const* d_in, const int* in_sizes, int n_in,
                              void* d_out, int out_size, void* d_ws, size_t ws_size,
                              hipStream_t stream)
{
    const long N = N_SP;
    const float* x      = (const float*)d_in[0];
    const float* cv1_w  = (const float*)d_in[1];
    const float* cv1_s  = (const float*)d_in[2];
    const float* cv1_b  = (const float*)d_in[3];
    const float* qkv_w  = (const float*)d_in[4];
    const float* qkv_s  = (const float*)d_in[5];
    const float* qkv_b  = (const float*)d_in[6];
    const float* pe_w   = (const float*)d_in[7];
    const float* pe_s   = (const float*)d_in[8];
    const float* pe_b   = (const float*)d_in[9];
    const float* proj_w = (const float*)d_in[10];
    const float* proj_s = (const float*)d_in[11];
    const float* proj_b = (const float*)d_in[12];
    const float* ffn1_w = (const float*)d_in[13];
    const float* ffn1_s = (const float*)d_in[14];
    const float* ffn1_b = (const float*)d_in[15];
    const float* ffn2_w = (const float*)d_in[16];
    const float* ffn2_s = (const float*)d_in[17];
    const float* ffn2_b = (const float*)d_in[18];
    const float* cv2_w  = (const float*)d_in[19];
    const float* cv2_s  = (const float*)d_in[20];
    const float* cv2_b  = (const float*)d_in[21];
    float* out = (float*)d_out;

    u16* ws = (u16*)d_ws;
    u16* xT      = ws;                       // [4][2304][512]
    u16* abT     = xT      + 4L * N * 512;   // [4][2304][512]
    u16* qkvb    = abT     + 4L * N * 512;   // [4][512][2304]
    u16* qkvT    = qkvb    + 4L * N * 512;   // [4][2304][512]
    u16* attnT   = qkvT    + 4L * N * 512;   // [4][2304][256]
    u16* bb2T    = attnT   + 4L * N * 256;   // [4][2304][256]
    u16* fT      = bb2T    + 4L * N * 256;   // [4][2304][512]
    u16* bb3T    = fT      + 4L * N * 512;   // [4][2304][256]
    u16* w_cv1   = bb3T    + 4L * N * 256;   // 512*512
    u16* w_qkv   = w_cv1   + 512L * 512;
    u16* w_proj  = w_qkv   + 512L * 256;
    u16* w_ffn1  = w_proj  + 256L * 256;
    u16* w_ffn2  = w_ffn1  + 512L * 256;
    u16* w_cv2   = w_ffn2  + 256L * 512;
    u16* Opart   = w_cv2   + 512L * 512;     // [4][16][64][2304] bf16
    float* mpart = (float*)(Opart + 4L * 16 * 64 * N);   // [4][16][2304]
    float* lpart = mpart + 4L * 16 * N;

    dim3 blk(256);
    const int BIGK = 1 << 28;

    // 0. merged weight-convert + x-transpose
    prep<<<2112, blk, 0, stream>>>(x, xT,
        cv1_w, qkv_w, proj_w, ffn1_w, ffn2_w, cv2_w,
        w_cv1, w_qkv, w_proj, w_ffn1, w_ffn2, w_cv2);

    // 1. abT = silu(cv1(x))^T   (128-row tile, single-round grid 576)
    mfma_gemm_big<8, 0><<<576, blk, 0, stream>>>(
        xT, nullptr, BIGK, 512, 0, 512, w_cv1, cv1_s, cv1_b,
        nullptr, 0, abT, nullptr, 512, 512, 1);

    // 2. qkvb normal [b][512][N]  +  qkvT transposed [b][N][512]
    mfma_gemm_big<8, 3><<<576, blk, 0, stream>>>(
        abT + 256, nullptr, BIGK, 512, 0, 256, w_qkv, qkv_s, qkv_b,
        nullptr, 0, qkvb, qkvT, 0, 512, 0);

    // 3. attention partials (split-j x4, 128 queries/block)
    attn_mfma<<<1152, blk, 0, stream>>>(qkvb, qkvT, Opart, mpart, lpart);

    // 4. combine + fused PE -> attnT [b][n][256]
    attn_combine<<<dim3(36, 16), blk, 0, stream>>>(
        Opart, mpart, lpart, qkvT, pe_w, pe_s, pe_b, attnT);

    // 5. bb2T = bb^T + proj(attn)^T   (64-tile kernel, single-round)
    mfma_gemm<4, 0><<<576, blk, 0, stream>>>(
        attnT, nullptr, BIGK, 256, 0, 256, w_proj, proj_s, proj_b,
        abT + 256, 512, bb2T, nullptr, 256, 256, 0);

    // 6. fT = silu(ffn1(bb2))^T   (128-row tile)
    mfma_gemm_big<8, 0><<<576, blk, 0, stream>>>(
        bb2T, nullptr, BIGK, 256, 0, 256, w_ffn1, ffn1_s, ffn1_b,
        nullptr, 0, fT, nullptr, 512, 512, 1);

    // 7. bb3T = bb2T + ffn2(f)^T   (64-tile kernel)
    mfma_gemm<4, 0><<<576, blk, 0, stream>>>(
        fT, nullptr, BIGK, 512, 0, 512, w_ffn2, ffn2_s, ffn2_b,
        bb2T, 256, bb3T, nullptr, 256, 256, 0);

    // 8. out = silu(cv2(concat(a, bb3)))  fp32 normal [b][512][N]  (128-row)
    mfma_gemm_big<8, 2><<<576, blk, 0, stream>>>(
        abT, bb3T, 256, 512, 256, 512, w_cv2, cv2_s, cv2_b,
        nullptr, 0, out, nullptr, 0, 512, 1);
}